// Round 14
// baseline (194.070 us; speedup 1.0000x reference)
//
// v14: v13 with stageA extent fix (QKV A-tile = 16KB -> 4 staging iterations).
#include <hip/hip_runtime.h>

#define SEQ   1024
#define HEADS 16
#define HD    64
#define BATCH 4
#define EMB   1024

typedef __attribute__((ext_vector_type(8))) short  short8;
typedef __attribute__((ext_vector_type(4))) float  floatx4;

__device__ __forceinline__ unsigned short f2bf(float f) {
    unsigned u = __builtin_bit_cast(unsigned, f);
    u += 0x7FFF + ((u >> 16) & 1);   // RNE
    return (unsigned short)(u >> 16);
}

__device__ __forceinline__ void g2l16(const void* g, void* l) {
    __builtin_amdgcn_global_load_lds((const __attribute__((address_space(1))) unsigned int*)g,
                                     (__attribute__((address_space(3))) unsigned int*)l,
                                     16, 0, 0);
}

// Read a 16B fragment from a swizzled [rows][64 bf16] LDS tile.
__device__ __forceinline__ short8 ldsfrag(const unsigned short* base, int row, int cq) {
    int ch = cq ^ (row & 7);
    return *(const short8*)(base + row * 64 + ch * 8);
}

// ---------------------------------------------------------------- convert + W fragment-pack
// blocks [0,4096): x f32->bf16 linear.
// blocks [4096,4480): Wqkv pack; blocks [4480,4608): Wo pack.
// Packed word w in [0,1024): ks=w>>9, jj=(w>>6)&7, lane=w&63 holds
//   W[n0t*128 + jj*16 + (lane&15)][kt*64 + ks*32 + (lane>>4)*8 + 0..7]  (16B).
// A wave reading word base ks*512+jj*64+lane is a coalesced 1KB load = one MFMA B-frag
// (mapping == the ldsfrag fragment: row = jj*16+l15, col chunk = ks*4+quad).
__global__ __launch_bounds__(256) void cvt_kernel(
    const float* __restrict__ x,  const float* __restrict__ wq,
    const float* __restrict__ wk, const float* __restrict__ wv,
    const float* __restrict__ wo,
    unsigned short* __restrict__ xb, unsigned short* __restrict__ wqkvP,
    unsigned short* __restrict__ woP) {
    int blk = blockIdx.x;
    int tid = threadIdx.x;
    if (blk < 4096) {
        size_t i = (size_t)blk * 1024 + tid * 4;
        float4 v = *(const float4*)(x + i);
        ushort4 o;
        o.x = f2bf(v.x); o.y = f2bf(v.y); o.z = f2bf(v.z); o.w = f2bf(v.w);
        *(ushort4*)(xb + i) = o;
        return;
    }
    int pblk = blk - 4096;
    const float* src; unsigned short* dst; int n0t, kt;
    if (pblk < 384) {
        n0t = pblk >> 4; kt = pblk & 15;
        int which = n0t >> 3;
        src = (which == 0) ? wq : (which == 1) ? wk : wv;
        src += (size_t)(n0t & 7) * 128 * 1024;
        dst = wqkvP + (size_t)pblk * 8192;
    } else {
        int p2 = pblk - 384;
        n0t = p2 >> 4; kt = p2 & 15;
        src = wo + (size_t)n0t * 128 * 1024;
        dst = woP + (size_t)p2 * 8192;
    }
#pragma unroll
    for (int s = 0; s < 4; s++) {
        int w    = tid * 4 + s;
        int ks   = w >> 9, jj = (w >> 6) & 7, lane = w & 63;
        int row  = jj * 16 + (lane & 15);
        int col  = kt * 64 + ks * 32 + (lane >> 4) * 8;
        const float* sp = src + (size_t)row * 1024 + col;
        float4 v0 = *(const float4*)sp;
        float4 v1 = *(const float4*)(sp + 4);
        ushort4 o0, o1;
        o0.x = f2bf(v0.x); o0.y = f2bf(v0.y); o0.z = f2bf(v0.z); o0.w = f2bf(v0.w);
        o1.x = f2bf(v1.x); o1.y = f2bf(v1.y); o1.z = f2bf(v1.z); o1.w = f2bf(v1.w);
        *(ushort4*)(dst + (size_t)w * 8)     = o0;
        *(ushort4*)(dst + (size_t)w * 8 + 4) = o1;
    }
}

// ---------------------------------------------------------------- QKV GEMM: A-dbuf + W-stream
// A staged in LDS (dbuf 2x16KB, single-barrier pipeline); B fragments streamed
// DIRECT from packed W (L2-resident, coalesced 1KB/wave). Per-step staged bytes
// 32KB->16KB. b8 issued FIRST (oldest, in-order vmcnt) + sched_barrier(0) so
// waiting on b8 never drains the younger A staging. XCD-chunked swizzle kept.
// Fused RoPE epilogue: Q,K -> [b][h][s][d]; V -> [b][h][d][s].
__global__ __launch_bounds__(256) void gemm_qkv(
    const unsigned short* __restrict__ A, const unsigned short* __restrict__ Wp,
    unsigned short* __restrict__ outQ, unsigned short* __restrict__ outK,
    unsigned short* __restrict__ outV, const float* __restrict__ rc,
    int M, int N, int K) {
    __shared__ unsigned short As[2][128 * 64];   // 2 x 16KB, swizzled
    const int tid  = threadIdx.x;
    const int lane = tid & 63;
    const int wid  = tid >> 6;
    const int l15  = lane & 15, quad = lane >> 4;
    const int wm   = (wid & 1) * 64, wn = (wid >> 1) * 64;
    // XCD-chunked swizzle (bijective: 768 % 8 == 0)
    const int nbx  = gridDim.x;
    const int cpx  = (nbx * gridDim.y) >> 3;
    const int bid  = blockIdx.y * nbx + blockIdx.x;
    const int virt = (bid & 7) * cpx + (bid >> 3);
    const int n0t  = virt % nbx;
    const int m0   = (virt / nbx) * 128, n0 = n0t * 128;
    const int boff = tid * 16;

    floatx4 acc[4][4] = {};
    const char* Ab = (const char*)A;
    const size_t rstride = (size_t)K * 2;
    const unsigned short* wpb = Wp + ((size_t)(wn >> 4) * 64 + lane) * 8;

    auto stageA = [&](int bufi, int k0) {
#pragma unroll
        for (int c = 0; c < 4; c++) {          // FIX: 128 rows x 64 cols x 2B = 16KB
            int o = c * 4096 + boff;
            int row = o >> 7;
            int sw  = ((o >> 4) & 7) ^ (row & 7);
            g2l16(Ab + (size_t)(m0 + row) * rstride + (size_t)k0 * 2 + sw * 16,
                  (char*)As[bufi] + o);
        }
    };

    stageA(0, 0);
    __syncthreads();

    int cur = 0;
    for (int k0 = 0; k0 < K; k0 += 64) {
        const int kt = k0 >> 6;
        // ---- B fragments direct from packed W (oldest vmem ops this step)
        const unsigned short* wp = wpb + (size_t)(n0t * 16 + kt) * 8192;
        short8 b8[2][4];
#pragma unroll
        for (int ks = 0; ks < 2; ks++)
#pragma unroll
            for (int j = 0; j < 4; j++)
                b8[ks][j] = *(const short8*)(wp + (ks * 512 + j * 64) * 8);
        __builtin_amdgcn_sched_barrier(0);   // keep b8 older than next staging
        // ---- stage NEXT A-tile (stays in flight past b8 waits)
        if (k0 + 64 < K) stageA(cur ^ 1, k0 + 64);

        const unsigned short* Ac = As[cur];
#pragma unroll
        for (int ks = 0; ks < 2; ks++) {
            short8 a[4];
#pragma unroll
            for (int i = 0; i < 4; i++) a[i] = ldsfrag(Ac, wm + i * 16 + l15, ks * 4 + quad);
#pragma unroll
            for (int i = 0; i < 4; i++)
#pragma unroll
                for (int j = 0; j < 4; j++)
                    acc[i][j] = __builtin_amdgcn_mfma_f32_16x16x32_bf16(a[i], b8[ks][j], acc[i][j], 0, 0, 0);
        }
        // ---- single barrier: next A landed + current A free
        asm volatile("s_waitcnt vmcnt(0)" ::: "memory");
        __syncthreads();
        cur ^= 1;
    }

    const int which = n0 >> 10;   // 0=Q 1=K 2=V (block-uniform)
#pragma unroll
    for (int i = 0; i < 4; i++) {
#pragma unroll
        for (int r = 0; r < 4; r++) {
            int m = m0 + wm + i * 16 + quad * 4 + r;
            int bb = m >> 10, s = m & 1023;
#pragma unroll
            for (int j = 0; j < 4; j++) {
                int n = n0 + wn + j * 16 + l15;
                float v = acc[i][j][r];
                int nr = n & 1023, h = nr >> 6, d = nr & 63;
                if (which < 2) {
                    // RoPE: pair (2i,2i+1) lives in lanes l15, l15^1
                    float vp = __shfl_xor(v, 1);
                    float2 cs = *(const float2*)&rc[(size_t)s * 64 + (d & ~1)];
                    v = (l15 & 1) ? (vp * cs.y + v * cs.x) : (v * cs.x - vp * cs.y);
                    unsigned short* dst = (which == 0) ? outQ : outK;
                    dst[(((size_t)bb * HEADS + h) * SEQ + s) * HD + d] = f2bf(v);
                } else {
                    outV[(((size_t)bb * HEADS + h) * HD + d) * SEQ + s] = f2bf(v);
                }
            }
        }
    }
}

// ---------------------------------------------------------------- proj GEMM: 64x128, A-dbuf + W-stream
__global__ __launch_bounds__(256) void gemm_proj64(
    const unsigned short* __restrict__ A, const unsigned short* __restrict__ Wp,
    float* __restrict__ out, int M, int N, int K) {
    __shared__ unsigned short As[2][64 * 64];    // 2 x 8KB, swizzled
    const int tid  = threadIdx.x;
    const int lane = tid & 63;
    const int wid  = tid >> 6;
    const int l15  = lane & 15, quad = lane >> 4;
    const int wm   = (wid & 1) * 32, wn = (wid >> 1) * 64;
    const int n0t  = blockIdx.x;
    const int m0   = blockIdx.y * 64, n0 = n0t * 128;
    const int boff = tid * 16;

    floatx4 acc[2][4] = {};
    const char* Ab = (const char*)A;
    const size_t rstride = (size_t)K * 2;
    const unsigned short* wpb = Wp + ((size_t)(wn >> 4) * 64 + lane) * 8;

    auto stageA = [&](int bufi, int k0) {
#pragma unroll
        for (int c = 0; c < 2; c++) {          // 64 rows x 64 cols x 2B = 8KB
            int o = c * 4096 + boff;
            int row = o >> 7;
            int sw  = ((o >> 4) & 7) ^ (row & 7);
            g2l16(Ab + (size_t)(m0 + row) * rstride + (size_t)k0 * 2 + sw * 16,
                  (char*)As[bufi] + o);
        }
    };

    stageA(0, 0);
    __syncthreads();

    int cur = 0;
    for (int k0 = 0; k0 < K; k0 += 64) {
        const int kt = k0 >> 6;
        const unsigned short* wp = wpb + (size_t)(n0t * 16 + kt) * 8192;
        short8 b8[2][4];
#pragma unroll
        for (int ks = 0; ks < 2; ks++)
#pragma unroll
            for (int j = 0; j < 4; j++)
                b8[ks][j] = *(const short8*)(wp + (ks * 512 + j * 64) * 8);
        __builtin_amdgcn_sched_barrier(0);
        if (k0 + 64 < K) stageA(cur ^ 1, k0 + 64);

        const unsigned short* Ac = As[cur];
#pragma unroll
        for (int ks = 0; ks < 2; ks++) {
            short8 a[2];
#pragma unroll
            for (int i = 0; i < 2; i++) a[i] = ldsfrag(Ac, wm + i * 16 + l15, ks * 4 + quad);
#pragma unroll
            for (int i = 0; i < 2; i++)
#pragma unroll
                for (int j = 0; j < 4; j++)
                    acc[i][j] = __builtin_amdgcn_mfma_f32_16x16x32_bf16(a[i], b8[ks][j], acc[i][j], 0, 0, 0);
        }
        asm volatile("s_waitcnt vmcnt(0)" ::: "memory");
        __syncthreads();
        cur ^= 1;
    }

#pragma unroll
    for (int i = 0; i < 2; i++) {
#pragma unroll
        for (int r = 0; r < 4; r++) {
            int m = m0 + wm + i * 16 + quad * 4 + r;
#pragma unroll
            for (int j = 0; j < 4; j++) {
                int n = n0 + wn + j * 16 + l15;
                out[(size_t)m * N + n] = acc[i][j][r];
            }
        }
    }
}

// ---------------------------------------------------------------- flash attention (r10 form)
__global__ __launch_bounds__(256) void attn_kernel(
    const unsigned short* __restrict__ Qb, const unsigned short* __restrict__ Kb,
    const unsigned short* __restrict__ VTb, const float* __restrict__ pm,
    unsigned short* __restrict__ Tb) {
    __shared__ unsigned short Ks[2][64 * 64];  // 2 x 8KB swizzled [kv][d]
    __shared__ unsigned short Vs[2][64 * 64];  // 2 x 8KB swizzled [d][kv]
    const int tid  = threadIdx.x;
    const int lane = tid & 63, wid = tid >> 6;
    const int l15  = lane & 15, quad = lane >> 4;
    const int bh   = blockIdx.x, b = bh >> 4;
    const int q0   = (15 - blockIdx.y) * 64;   // heavy tiles dispatch first
    const int qw   = q0 + wid * 16;
    const int q    = qw + l15;
    const unsigned short* Qh  = Qb  + (size_t)bh * SEQ * HD;
    const unsigned short* Kh  = Kb  + (size_t)bh * SEQ * HD;
    const unsigned short* VTh = VTb + (size_t)bh * HD * SEQ;
    unsigned short*       Th  = Tb  + (size_t)bh * HD * SEQ;
    const float* pmb = pm + b * SEQ;
    const float SCL2 = 0.125f * 1.44269504088896340736f;   // (1/sqrt(64))*log2(e)

    short8 qf0 = *(const short8*)&Qh[(size_t)q * HD + quad * 8];
    short8 qf1 = *(const short8*)&Qh[(size_t)q * HD + 32 + quad * 8];

    floatx4 ot[4] = {};
    float l_lane = 0.f;
    const int boff = tid * 16;
    const int srcA = l15 + ((quad & 1) << 5);   // P-shuffle source lanes
    const int srcB = srcA + 16;
    const bool hi  = (quad >> 1) & 1;           // selects register st = quad>>1

    auto stageKV = [&](int bufi, int kvc) {
        const char* kg = (const char*)(Kh + (size_t)kvc * HD);
        const char* vg = (const char*)(VTh + kvc);
#pragma unroll
        for (int c = 0; c < 2; c++) {
            int o = c * 4096 + boff;
            int row = o >> 7;
            int sw  = ((o >> 4) & 7) ^ (row & 7);
            g2l16(kg + (size_t)row * 128 + sw * 16, (char*)Ks[bufi] + o);
            g2l16(vg + (size_t)row * (SEQ * 2) + sw * 16, (char*)Vs[bufi] + o);
        }
    };

    stageKV(0, 0);
    __syncthreads();

    int cur = 0;
    for (int kvc = 0; kvc <= q0; kvc += 64) {
        if (kvc + 64 <= q0) stageKV(cur ^ 1, kvc + 64);

        const unsigned short* Kc = Ks[cur];
        const unsigned short* Vc = Vs[cur];
        const bool diag = (kvc + 63 > qw);
        floatx4 sc[4];
#pragma unroll
        for (int st = 0; st < 4; st++) {
            short8 ka0 = ldsfrag(Kc, st * 16 + l15, quad);
            short8 ka1 = ldsfrag(Kc, st * 16 + l15, 4 + quad);
            floatx4 z = {0.f, 0.f, 0.f, 0.f};
            z = __builtin_amdgcn_mfma_f32_16x16x32_bf16(ka0, qf0, z, 0, 0, 0);
            z = __builtin_amdgcn_mfma_f32_16x16x32_bf16(ka1, qf1, z, 0, 0, 0);
            sc[st] = z;
        }
        unsigned w0[4], w1[4];
#pragma unroll
        for (int st = 0; st < 4; st++) {
            int kvbase = kvc + st * 16 + quad * 4;
            float4 pmv = *(const float4*)&pmb[kvbase];
            float p[4];
#pragma unroll
            for (int r = 0; r < 4; r++) {
                float e = exp2f(sc[st][r] * SCL2) * (((&pmv.x)[r] != 0.f) ? 1.f : 0.f);
                if (diag && (kvbase + r > q)) e = 0.f;
                l_lane += e;
                p[r] = e;
            }
            w0[st] = (unsigned)f2bf(p[0]) | ((unsigned)f2bf(p[1]) << 16);
            w1[st] = (unsigned)f2bf(p[2]) | ((unsigned)f2bf(p[3]) << 16);
        }
        unsigned a0 = __shfl(w0[0], srcA), a1 = __shfl(w0[1], srcA);
        unsigned b0 = __shfl(w1[0], srcA), b1 = __shfl(w1[1], srcA);
        unsigned c0 = __shfl(w0[0], srcB), c1 = __shfl(w0[1], srcB);
        unsigned d0 = __shfl(w1[0], srcB), d1 = __shfl(w1[1], srcB);
        uint4 f0 = { hi ? a1 : a0, hi ? b1 : b0, hi ? c1 : c0, hi ? d1 : d0 };
        short8 pf0 = __builtin_bit_cast(short8, f0);
        a0 = __shfl(w0[2], srcA); a1 = __shfl(w0[3], srcA);
        b0 = __shfl(w1[2], srcA); b1 = __shfl(w1[3], srcA);
        c0 = __shfl(w0[2], srcB); c1 = __shfl(w0[3], srcB);
        d0 = __shfl(w1[2], srcB); d1 = __shfl(w1[3], srcB);
        uint4 f1 = { hi ? a1 : a0, hi ? b1 : b0, hi ? c1 : c0, hi ? d1 : d0 };
        short8 pf1 = __builtin_bit_cast(short8, f1);

#pragma unroll
        for (int jt = 0; jt < 4; jt++) {
            short8 v0 = ldsfrag(Vc, jt * 16 + l15, quad);
            short8 v1 = ldsfrag(Vc, jt * 16 + l15, 4 + quad);
            ot[jt] = __builtin_amdgcn_mfma_f32_16x16x32_bf16(v0, pf0, ot[jt], 0, 0, 0);
            ot[jt] = __builtin_amdgcn_mfma_f32_16x16x32_bf16(v1, pf1, ot[jt], 0, 0, 0);
        }

        asm volatile("s_waitcnt vmcnt(0)" ::: "memory");
        __syncthreads();
        cur ^= 1;
    }

    float l = l_lane;
    l += __shfl_xor(l, 16);
    l += __shfl_xor(l, 32);
    float inv = 1.0f / l;
#pragma unroll
    for (int jt = 0; jt < 4; jt++)
#pragma unroll
        for (int r = 0; r < 4; r++)
            Th[(size_t)(jt * 16 + quad * 4 + r) * SEQ + q] = f2bf(ot[jt][r] * inv);
}

// ---------------------------------------------------------------- launch
extern "C" void kernel_launch(void* const* d_in, const int* in_sizes, int n_in,
                              void* d_out, int out_size, void* d_ws, size_t ws_size,
                              hipStream_t stream) {
    const float* x  = (const float*)d_in[0];
    const float* pm = (const float*)d_in[1];
    const float* Wq = (const float*)d_in[2];
    const float* Wk = (const float*)d_in[3];
    const float* Wv = (const float*)d_in[4];
    const float* Wo = (const float*)d_in[5];
    const float* rc = (const float*)d_in[6];

    char* base = (char*)d_ws;
    unsigned short* xb    = (unsigned short*)(base);                   //  8 MB
    unsigned short* wqkvP = (unsigned short*)(base + (8u  << 20));     //  6 MB packed
    unsigned short* woP   = (unsigned short*)(base + (14u << 20));     //  2 MB packed
    unsigned short* Qb    = (unsigned short*)(base + (16u << 20));     //  8 MB [b][h][s][d]
    unsigned short* Kb    = (unsigned short*)(base + (24u << 20));     //  8 MB [b][h][s][d]
    unsigned short* VTb   = (unsigned short*)(base + (32u << 20));     //  8 MB [b][h][d][s]
    unsigned short* Tb    = (unsigned short*)(base + (40u << 20));     //  8 MB [b][h][d][q]

    cvt_kernel<<<4608, 256, 0, stream>>>(x, Wq, Wk, Wv, Wo, xb, wqkvP, woP);
    gemm_qkv<<<dim3(24, 32), 256, 0, stream>>>(xb, wqkvP, Qb, Kb, VTb,
                                               rc, 4096, 3072, 1024);
    attn_kernel<<<dim3(64, 16), 256, 0, stream>>>(Qb, Kb, VTb, pm, Tb);
    gemm_proj64<<<dim3(8, 64), 256, 0, stream>>>(Tb, woP, (float*)d_out, 4096, 1024, 1024);
}